// Round 9
// baseline (8142.821 us; speedup 1.0000x reference)
//
#include <hip/hip_runtime.h>

#define LSEQ 2048
#define TAGS 12

typedef _Float16 half2v __attribute__((ext_vector_type(2)));
typedef unsigned u32x4 __attribute__((ext_vector_type(4)));
typedef unsigned long long u64;

__device__ __forceinline__ float sigm(float x){ return 1.0f/(1.0f+__expf(-x)); }
__device__ __forceinline__ float tanh_fast(float x){ return 1.0f - 2.0f/(1.0f+__expf(2.0f*x)); }
__device__ __forceinline__ half2v pack2(float a, float b){
  half2v r; r.x=(_Float16)a; r.y=(_Float16)b; return r;
}
__device__ __forceinline__ half2v h2(unsigned u){ return __builtin_bit_cast(half2v, u); }

// Raw workgroup barrier: orders LDS only (lgkmcnt), does NOT drain vmcnt
// (xg prefetch + history stores stay in flight across it).
__device__ __forceinline__ void wg_barrier(){
  asm volatile("s_waitcnt lgkmcnt(0)" ::: "memory");
  __builtin_amdgcn_s_barrier();
  __builtin_amdgcn_sched_barrier(0);
  asm volatile("" ::: "memory");
}

// K1: xg[d][t][row] = b_ih[row]+b_hh[row] + sum_e embed[sent[t]][e] * w_ih[row][e]
__global__ void xg_kernel(
    const int* sent, const float* embed,
    const float* w_ih_f, const float* b_ih_f, const float* b_hh_f,
    const float* w_ih_b, const float* b_ih_b, const float* b_hh_b,
    float* xg)
{
  __shared__ float x_sh[8][256];
  int tid = threadIdx.x;
  int t0 = blockIdx.x * 8;
  for (int i=0;i<8;++i){
    int idx = sent[t0+i];
    x_sh[i][tid] = embed[(size_t)idx*256 + tid];
  }
  __syncthreads();
  for (int ri=0; ri<8; ++ri){
    int r = ri*256 + tid;
    int d = r >> 10;
    int row = r & 1023;
    const float* wr = (d ? w_ih_b : w_ih_f) + (size_t)row*256;
    const float* bi = d ? b_ih_b : b_ih_f;
    const float* bh = d ? b_hh_b : b_hh_f;
    float acc[8];
    #pragma unroll
    for (int i=0;i<8;++i) acc[i]=0.f;
    for (int k0=0;k0<256;k0+=4){
      float4 p = *(const float4*)(wr + k0);
      #pragma unroll
      for (int i=0;i<8;++i){
        acc[i] += p.x*x_sh[i][k0] + p.y*x_sh[i][k0+1]
                + p.z*x_sh[i][k0+2] + p.w*x_sh[i][k0+3];
      }
    }
    float bias = bi[row] + bh[row];
    #pragma unroll
    for (int i=0;i<8;++i)
      xg[((size_t)d*LSEQ + (size_t)(t0+i))*1024 + row] = acc[i] + bias;
  }
}

// K2: bidirectional LSTM recurrence — SINGLE CU PER DIRECTION, no exchange.
// Rounds 0-8 (7 exchange mechanisms, all 2770-5130 us) proved the inter-CU
// signal round trip (~2000 cy: ~1000 publish-to-MALL + ~900/probe detect)
// is a hardware floor that sits on the recurrence critical path in ANY
// multi-CU design. Fix: fit a whole direction on ONE CU.
//  - 512 threads = 8 waves (2/SIMD), 2 gate-rows/thread (rows t, t+512).
//  - weights as f16 pairs: 96 pairs/row in VGPRs (192 regs/thread) + 32
//    pairs/row in LDS (128 KB, [group][row][4] -> 16B lane stride,
//    conflict-free ds_read_b128). Total LDS 136 KB <= 160.
//  - h: 128 pairs = 2/lane (hp0,hp1), REPLICATED in-register across all 8
//    waves (deterministic update) -> broadcast via readlane, shared by both
//    rows: 128 rl + 256 fdot2 per wave per step ~ 950 cy issue, x2
//    waves/SIMD ~ 1900 cy/SIMD -> VALU-bound, ~2000 cy/step total.
//  - ONE light barrier per step (lgkmcnt-only), two-parity gate buffer.
//    Safety: a wave writing gates(s+2) passed barrier(s+1); every wave
//    enters barrier(s+1) only after its gate-write(s+1), which follows
//    update(s) in program order -> update(s)'s reads of gate_sh[par] are
//    complete before any same-parity overwrite.
//  - zero global traffic in the loop except the xg prefetch (1 step ahead,
//    fire-and-forget) and wave0's h-history store.
__global__ __launch_bounds__(512,2) void lstm_rec(
    const float* __restrict__ w_hh_f, const float* __restrict__ w_hh_b,
    const float* __restrict__ xg, unsigned short* __restrict__ hstH)
{
  int d = blockIdx.x;               // 0: forward, 1: backward
  int t = threadIdx.x;              // 0..511
  int l = t & 63;
  int row0 = t;                     // gates i (t<256) / f (t>=256)
  int row1 = t + 512;               // gates g (t<256) / o (t>=256)
  const float* W = d ? w_hh_b : w_hh_f;
  const float* xgd = xg + (size_t)d*LSEQ*1024;
  unsigned short* hd = hstH + (size_t)d*LSEQ*256;

  __shared__ unsigned wlds[8][1024][4];  // 128 KB: weight pairs 96..127
  __shared__ float gate_sh[2][1024];     // 8 KB: parity x [row]

  // VGPR weights: pairs 0..95 for both rows (192 regs).
  half2v wA[96], wB[96];
  {
    const float* pr0 = W + (size_t)row0*256;
    const float* pr1 = W + (size_t)row1*256;
    #pragma unroll
    for (int k2=0;k2<48;++k2){
      float4 a = *(const float4*)(pr0 + 4*k2);
      wA[2*k2] = pack2(a.x,a.y); wA[2*k2+1] = pack2(a.z,a.w);
      float4 b = *(const float4*)(pr1 + 4*k2);
      wB[2*k2] = pack2(b.x,b.y); wB[2*k2+1] = pack2(b.z,b.w);
    }
    // LDS weights: pairs 96..127 (cols 192..255), 8 groups of 4 pairs.
    for (int jg=0;jg<8;++jg){
      float4 a0 = *(const float4*)(pr0 + 192 + 8*jg);
      float4 a1 = *(const float4*)(pr0 + 192 + 8*jg + 4);
      wlds[jg][row0][0] = __builtin_bit_cast(unsigned, pack2(a0.x,a0.y));
      wlds[jg][row0][1] = __builtin_bit_cast(unsigned, pack2(a0.z,a0.w));
      wlds[jg][row0][2] = __builtin_bit_cast(unsigned, pack2(a1.x,a1.y));
      wlds[jg][row0][3] = __builtin_bit_cast(unsigned, pack2(a1.z,a1.w));
      float4 b0 = *(const float4*)(pr1 + 192 + 8*jg);
      float4 b1 = *(const float4*)(pr1 + 192 + 8*jg + 4);
      wlds[jg][row1][0] = __builtin_bit_cast(unsigned, pack2(b0.x,b0.y));
      wlds[jg][row1][1] = __builtin_bit_cast(unsigned, pack2(b0.z,b0.w));
      wlds[jg][row1][2] = __builtin_bit_cast(unsigned, pack2(b1.x,b1.y));
      wlds[jg][row1][3] = __builtin_bit_cast(unsigned, pack2(b1.z,b1.w));
    }
  }
  // h state: lane l holds pairs 2l (hp0) and 2l+1 (hp1) = units 4l..4l+3,
  // replicated across all 8 waves. Cell state likewise (c0..c3).
  unsigned hp0 = 0u, hp1 = 0u;
  float c0=0.f, c1=0.f, c2=0.f, c3=0.f;
  __syncthreads();

  int tf = d ? (LSEQ-1) : 0;
  float xga = xgd[(size_t)tf*1024 + row0];
  float xgb = xgd[(size_t)tf*1024 + row1];

  for (int s=0;s<LSEQ;++s){
    int par = s & 1;
    // --- dot: VGPR part, pairs 0..95 (pair p lives in lane p>>1, reg p&1)
    float a0 = xga, b0 = 0.f, a1 = xgb, b1 = 0.f;
    #pragma unroll
    for (int j=0;j<48;++j){
      unsigned h0v = __builtin_amdgcn_readlane(hp0, j);
      unsigned h1v = __builtin_amdgcn_readlane(hp1, j);
      a0 = __builtin_amdgcn_fdot2(h2(h0v), wA[2*j],   a0, false);
      b0 = __builtin_amdgcn_fdot2(h2(h1v), wA[2*j+1], b0, false);
      a1 = __builtin_amdgcn_fdot2(h2(h0v), wB[2*j],   a1, false);
      b1 = __builtin_amdgcn_fdot2(h2(h1v), wB[2*j+1], b1, false);
    }
    // --- xg prefetch for s+1 (fire-and-forget; wait lands next iteration)
    int tn = (s+1 < LSEQ) ? (d ? (LSEQ-2-s) : (s+1)) : tf;
    float nxa = xgd[(size_t)tn*1024 + row0];
    float nxb = xgd[(size_t)tn*1024 + row1];
    // --- dot: LDS part, pairs 96..127 (8 groups x 4 pairs, 2x b128/group)
    #pragma unroll
    for (int jg=0;jg<8;++jg){
      u32x4 ga = *(const u32x4*)&wlds[jg][row0][0];
      u32x4 gb = *(const u32x4*)&wlds[jg][row1][0];
      unsigned h0v = __builtin_amdgcn_readlane(hp0, 48+2*jg);
      unsigned h1v = __builtin_amdgcn_readlane(hp1, 48+2*jg);
      unsigned h2v = __builtin_amdgcn_readlane(hp0, 49+2*jg);
      unsigned h3v = __builtin_amdgcn_readlane(hp1, 49+2*jg);
      a0 = __builtin_amdgcn_fdot2(h2(h0v), h2(ga[0]), a0, false);
      b0 = __builtin_amdgcn_fdot2(h2(h1v), h2(ga[1]), b0, false);
      a0 = __builtin_amdgcn_fdot2(h2(h2v), h2(ga[2]), a0, false);
      b0 = __builtin_amdgcn_fdot2(h2(h3v), h2(ga[3]), b0, false);
      a1 = __builtin_amdgcn_fdot2(h2(h0v), h2(gb[0]), a1, false);
      b1 = __builtin_amdgcn_fdot2(h2(h1v), h2(gb[1]), b1, false);
      a1 = __builtin_amdgcn_fdot2(h2(h2v), h2(gb[2]), a1, false);
      b1 = __builtin_amdgcn_fdot2(h2(h3v), h2(gb[3]), b1, false);
    }
    float pre0 = a0 + b0, pre1 = a1 + b1;
    float act0 = sigm(pre0);                                // i or f
    float act1 = (t < 256) ? tanh_fast(pre1) : sigm(pre1);  // g or o
    gate_sh[par][row0] = act0;
    gate_sh[par][row1] = act1;
    wg_barrier();                    // gates(s) visible to all waves
    // --- update: units 4l..4l+3, replicated on ALL lanes of ALL waves
    {
      const float* gp = gate_sh[par];
      float4 gi = *(const float4*)&gp[       4*l];
      float4 gf = *(const float4*)&gp[256 +  4*l];
      float4 gg = *(const float4*)&gp[512 +  4*l];
      float4 go = *(const float4*)&gp[768 +  4*l];
      c0 = gf.x*c0 + gi.x*gg.x;
      c1 = gf.y*c1 + gi.y*gg.y;
      c2 = gf.z*c2 + gi.z*gg.z;
      c3 = gf.w*c3 + gi.w*gg.w;
      float h0 = go.x * tanh_fast(c0);
      float h1 = go.y * tanh_fast(c1);
      float h2_ = go.z * tanh_fast(c2);
      float h3 = go.w * tanh_fast(c3);
      hp0 = __builtin_bit_cast(unsigned, pack2(h0,h1));
      hp1 = __builtin_bit_cast(unsigned, pack2(h2_,h3));
    }
    // --- wave0: h-history store (fire-and-forget; nothing drains it)
    if (t < 64){
      int tp = d ? (LSEQ-1-s) : s;
      uint2 hv; hv.x = hp0; hv.y = hp1;
      *(uint2*)&hd[(size_t)tp*256 + 4*l] = hv;
    }
    xga = nxa; xgb = nxb;
    // no second barrier: next write targets gate_sh[par^1]; same-parity
    // reuse at s+2 is ordered by barrier(s+1) (see header comment).
  }
}

// K3: feats[t][tag] = b_out[tag] + [hf|hb] . w_out[tag]   (h history is f16)
__global__ void feats_kernel(
    const unsigned short* hstH, const float* w_out, const float* b_out,
    float* feats)
{
  __shared__ float w_sh[12*520];
  __shared__ float h_sh[16*520];
  const _Float16* hf = (const _Float16*)hstH;
  int tid=threadIdx.x;
  int t0=blockIdx.x*16;
  for (int i=tid;i<12*512;i+=256){ int tag=i>>9,k=i&511; w_sh[tag*520+k]=w_out[i]; }
  for (int i=tid;i<16*512;i+=256){
    int tt=i>>9,k=i&511;
    float v = (k<256)? (float)hf[(size_t)(t0+tt)*256+k]
                     : (float)hf[(size_t)(LSEQ+t0+tt)*256 + (k-256)];
    h_sh[tt*520+k]=v;
  }
  __syncthreads();
  if (tid<192){
    int tt=tid/12, tag=tid%12;
    const float* wr=&w_sh[tag*520];
    const float* hr=&h_sh[tt*520];
    float acc=b_out[tag];
    for (int k=0;k<512;k+=4){
      float4 a=*(const float4*)(wr+k);
      float4 b=*(const float4*)(hr+k);
      acc += a.x*b.x+a.y*b.y+a.z*b.z+a.w*b.w;
    }
    feats[(size_t)(t0+tt)*12+tag]=acc;
  }
}

// K4: Viterbi DP: feats in LDS, v register-resident via readlane; parallel
// block-composed backtrack.
__global__ void BiLSTM_CRF_14405320311361_kernel(
    const float* feats, const float* trans, float* outp)
{
  __shared__ float fsh[LSEQ*12];           // 96 KB
  __shared__ unsigned char bps[LSEQ*12];   // 24 KB
  __shared__ float term_sh[16];
  __shared__ int ibuf[66];
  __shared__ unsigned char fmap[64*12];
  int tid = threadIdx.x;
  for (int i=tid; i<LSEQ*12/4; i+=256)
    *(float4*)&fsh[4*i] = *(const float4*)&feats[4*i];
  __syncthreads();

  int lane = tid & 63;
  int fl = (lane<12) ? lane : 0;
  float vn = 0.f;
  if (tid < 64){
    float tr[12];
    #pragma unroll
    for (int p=0;p<12;++p) tr[p] = trans[fl*12+p];
    vn = (lane==10) ? 0.f : -10000.f;     // START=10
    float fa = fsh[fl];
    float fb = fsh[12+fl];
    for (int t=0;t<LSEQ;++t){
      unsigned vu = __float_as_uint(vn);
      float best; int bp; float sc;
      best = tr[0] + __uint_as_float(__builtin_amdgcn_readlane(vu,0)); bp = 0;
      sc = tr[1]  + __uint_as_float(__builtin_amdgcn_readlane(vu,1));  if(sc>best){best=sc;bp=1;}
      sc = tr[2]  + __uint_as_float(__builtin_amdgcn_readlane(vu,2));  if(sc>best){best=sc;bp=2;}
      sc = tr[3]  + __uint_as_float(__builtin_amdgcn_readlane(vu,3));  if(sc>best){best=sc;bp=3;}
      sc = tr[4]  + __uint_as_float(__builtin_amdgcn_readlane(vu,4));  if(sc>best){best=sc;bp=4;}
      sc = tr[5]  + __uint_as_float(__builtin_amdgcn_readlane(vu,5));  if(sc>best){best=sc;bp=5;}
      sc = tr[6]  + __uint_as_float(__builtin_amdgcn_readlane(vu,6));  if(sc>best){best=sc;bp=6;}
      sc = tr[7]  + __uint_as_float(__builtin_amdgcn_readlane(vu,7));  if(sc>best){best=sc;bp=7;}
      sc = tr[8]  + __uint_as_float(__builtin_amdgcn_readlane(vu,8));  if(sc>best){best=sc;bp=8;}
      sc = tr[9]  + __uint_as_float(__builtin_amdgcn_readlane(vu,9));  if(sc>best){best=sc;bp=9;}
      sc = tr[10] + __uint_as_float(__builtin_amdgcn_readlane(vu,10)); if(sc>best){best=sc;bp=10;}
      sc = tr[11] + __uint_as_float(__builtin_amdgcn_readlane(vu,11)); if(sc>best){best=sc;bp=11;}
      vn = best + fa;
      fa = fb;
      if (t+2 < LSEQ) fb = fsh[(t+2)*12+fl];
      if (lane<12) bps[t*12+lane] = (unsigned char)bp;
    }
  }
  if (tid < 12) term_sh[tid] = vn + trans[11*12+tid];   // STOP=11
  __syncthreads();
  if (tid == 0){
    float bs=term_sh[0]; int bt=0;
    for (int p=1;p<12;++p){ if (term_sh[p]>bs){bs=term_sh[p];bt=p;} }
    outp[0] = bs;
    ibuf[64] = bt;
  }
  __syncthreads();
  if (tid < 64){
    int b = tid;
    int f[12];
    int thi = b*32+31;
    #pragma unroll
    for (int x=0;x<12;++x) f[x] = bps[thi*12+x];
    for (int t=thi-1; t>=b*32; --t){
      int base = t*12;
      #pragma unroll
      for (int x=0;x<12;++x) f[x] = bps[base + f[x]];
    }
    #pragma unroll
    for (int x=0;x<12;++x) fmap[b*12+x] = (unsigned char)f[x];
  }
  __syncthreads();
  if (tid == 0){
    int tag = ibuf[64];
    for (int b=63;b>=0;--b){ ibuf[b]=tag; tag = fmap[b*12+tag]; }
  }
  __syncthreads();
  if (tid < 64){
    int b = tid;
    int tag = ibuf[b];
    for (int t=b*32+31; t>=b*32; --t){
      outp[1+t] = (float)tag;
      tag = bps[t*12+tag];
    }
  }
}

extern "C" void kernel_launch(void* const* d_in, const int* in_sizes, int n_in,
                              void* d_out, int out_size, void* d_ws, size_t ws_size,
                              hipStream_t stream) {
  const int*   sent   = (const int*)d_in[0];
  const float* embed  = (const float*)d_in[1];
  const float* w_ih_f = (const float*)d_in[2];
  const float* w_hh_f = (const float*)d_in[3];
  const float* b_ih_f = (const float*)d_in[4];
  const float* b_hh_f = (const float*)d_in[5];
  const float* w_ih_b = (const float*)d_in[6];
  const float* w_hh_b = (const float*)d_in[7];
  const float* b_ih_b = (const float*)d_in[8];
  const float* b_hh_b = (const float*)d_in[9];
  const float* w_out  = (const float*)d_in[10];
  const float* b_out  = (const float*)d_in[11];
  const float* trans  = (const float*)d_in[12];

  float* xg = (float*)d_ws;                                           // [2][L][1024] f32 = 16 MB
  unsigned short* hstH = (unsigned short*)(xg + (size_t)2*LSEQ*1024); // [2][L][256] f16 = 2 MB
  float* feats = (float*)(hstH + (size_t)2*LSEQ*256);                 // [L][12] f32 = 96 KB
  float* outp  = (float*)d_out;

  xg_kernel<<<dim3(LSEQ/8), dim3(256), 0, stream>>>(
      sent, embed, w_ih_f, b_ih_f, b_hh_f, w_ih_b, b_ih_b, b_hh_b, xg);
  lstm_rec<<<dim3(2), dim3(512), 0, stream>>>(w_hh_f, w_hh_b, xg, hstH);
  feats_kernel<<<dim3(LSEQ/16), dim3(256), 0, stream>>>(hstH, w_out, b_out, feats);
  BiLSTM_CRF_14405320311361_kernel<<<dim3(1), dim3(256), 0, stream>>>(feats, trans, outp);
}

// Round 10
// 5802.214 us; speedup vs baseline: 1.4034x; 1.4034x over previous
//
#include <hip/hip_runtime.h>

#define LSEQ 2048
#define TAGS 12

typedef _Float16 half2v __attribute__((ext_vector_type(2)));
typedef unsigned u32x4 __attribute__((ext_vector_type(4)));

__device__ __forceinline__ float sigm(float x){ return 1.0f/(1.0f+__expf(-x)); }
__device__ __forceinline__ float tanh_fast(float x){ return 1.0f - 2.0f/(1.0f+__expf(2.0f*x)); }
__device__ __forceinline__ half2v pack2(float a, float b){
  half2v r; r.x=(_Float16)a; r.y=(_Float16)b; return r;
}
__device__ __forceinline__ half2v h2(unsigned u){ return __builtin_bit_cast(half2v, u); }

// Raw workgroup barrier: orders LDS only (lgkmcnt), does NOT drain vmcnt
// (xg prefetch + history stores stay in flight across it).
__device__ __forceinline__ void wg_barrier(){
  asm volatile("s_waitcnt lgkmcnt(0)" ::: "memory");
  __builtin_amdgcn_s_barrier();
  __builtin_amdgcn_sched_barrier(0);
  asm volatile("" ::: "memory");
}

// K1: xg[d][t][row] = b_ih[row]+b_hh[row] + sum_e embed[sent[t]][e] * w_ih[row][e]
__global__ void xg_kernel(
    const int* sent, const float* embed,
    const float* w_ih_f, const float* b_ih_f, const float* b_hh_f,
    const float* w_ih_b, const float* b_ih_b, const float* b_hh_b,
    float* xg)
{
  __shared__ float x_sh[8][256];
  int tid = threadIdx.x;
  int t0 = blockIdx.x * 8;
  for (int i=0;i<8;++i){
    int idx = sent[t0+i];
    x_sh[i][tid] = embed[(size_t)idx*256 + tid];
  }
  __syncthreads();
  for (int ri=0; ri<8; ++ri){
    int r = ri*256 + tid;
    int d = r >> 10;
    int row = r & 1023;
    const float* wr = (d ? w_ih_b : w_ih_f) + (size_t)row*256;
    const float* bi = d ? b_ih_b : b_ih_f;
    const float* bh = d ? b_hh_b : b_hh_f;
    float acc[8];
    #pragma unroll
    for (int i=0;i<8;++i) acc[i]=0.f;
    for (int k0=0;k0<256;k0+=4){
      float4 p = *(const float4*)(wr + k0);
      #pragma unroll
      for (int i=0;i<8;++i){
        acc[i] += p.x*x_sh[i][k0] + p.y*x_sh[i][k0+1]
                + p.z*x_sh[i][k0+2] + p.w*x_sh[i][k0+3];
      }
    }
    float bias = bi[row] + bh[row];
    #pragma unroll
    for (int i=0;i<8;++i)
      xg[((size_t)d*LSEQ + (size_t)(t0+i))*1024 + row] = acc[i] + bias;
  }
}

// K2: bidirectional LSTM recurrence — SINGLE CU PER DIRECTION, no exchange.
// (Structure HW-validated in round 9: passed refcheck; exchange traffic gone.)
// Round-9 failure mode: VGPR_Count=128 with 192 declared weight regs ->
// the two 96-element half2v arrays were NOT promoted; they lived in scratch
// (786 KB/step reload -> 7540us + 38ms warm-up outlier). Fixes:
//  1. weights in SIX 32-element arrays (r0 proved 128-elem promotes; 32 is
//     trivially SROA-friendly), all indices compile-time after unroll.
//  2. __attribute__((amdgpu_waves_per_eu(2,2))): pin the allocator to
//     2 waves/EU (the block's own residency: 512 thr = 8 waves / 4 SIMDs)
//     -> register budget 512/2 = 256; live set ~225. Round 9's 128 = the
//     allocator targeting 4 waves/EU it was never asked for.
// Recap of the design:
//  - 512 threads, 2 gate-rows/thread (rows t, t+512).
//  - 96 pairs/row in VGPRs (192 regs) + 32 pairs/row in LDS (128 KB,
//    [group][row][4] -> 16B lane stride, conflict-free ds_read_b128).
//  - h: 128 pairs = 2/lane (hp0,hp1), replicated in-register across all 8
//    waves (deterministic update) -> readlane broadcast shared by both rows.
//  - ONE light barrier/step, two-parity gate buffer. Safety: a wave writing
//    gates(s+2) passed barrier(s+1), entered only after update(s).
//  - loop global traffic: xg prefetch (1 step ahead) + wave0 h-history only.
__global__ __launch_bounds__(512)
__attribute__((amdgpu_waves_per_eu(2,2)))
void lstm_rec(
    const float* __restrict__ w_hh_f, const float* __restrict__ w_hh_b,
    const float* __restrict__ xg, unsigned short* __restrict__ hstH)
{
  int d = blockIdx.x;               // 0: forward, 1: backward
  int t = threadIdx.x;              // 0..511
  int l = t & 63;
  int row0 = t;                     // gates i (t<256) / f (t>=256)
  int row1 = t + 512;               // gates g (t<256) / o (t>=256)
  const float* W = d ? w_hh_b : w_hh_f;
  const float* xgd = xg + (size_t)d*LSEQ*1024;
  unsigned short* hd = hstH + (size_t)d*LSEQ*256;

  __shared__ unsigned wlds[8][1024][4];  // 128 KB: weight pairs 96..127
  __shared__ float gate_sh[2][1024];     // 8 KB: parity x [row]

  // VGPR weights: pairs 0..95 per row, as 3x32-element arrays per row.
  half2v wA0[32], wA1[32], wA2[32], wB0[32], wB1[32], wB2[32];
  {
    const float* pr0 = W + (size_t)row0*256;
    const float* pr1 = W + (size_t)row1*256;
    #pragma unroll
    for (int k2=0;k2<16;++k2){
      float4 a = *(const float4*)(pr0 + 4*k2);
      wA0[2*k2] = pack2(a.x,a.y); wA0[2*k2+1] = pack2(a.z,a.w);
      float4 b = *(const float4*)(pr1 + 4*k2);
      wB0[2*k2] = pack2(b.x,b.y); wB0[2*k2+1] = pack2(b.z,b.w);
    }
    #pragma unroll
    for (int k2=0;k2<16;++k2){
      float4 a = *(const float4*)(pr0 + 64 + 4*k2);
      wA1[2*k2] = pack2(a.x,a.y); wA1[2*k2+1] = pack2(a.z,a.w);
      float4 b = *(const float4*)(pr1 + 64 + 4*k2);
      wB1[2*k2] = pack2(b.x,b.y); wB1[2*k2+1] = pack2(b.z,b.w);
    }
    #pragma unroll
    for (int k2=0;k2<16;++k2){
      float4 a = *(const float4*)(pr0 + 128 + 4*k2);
      wA2[2*k2] = pack2(a.x,a.y); wA2[2*k2+1] = pack2(a.z,a.w);
      float4 b = *(const float4*)(pr1 + 128 + 4*k2);
      wB2[2*k2] = pack2(b.x,b.y); wB2[2*k2+1] = pack2(b.z,b.w);
    }
    // LDS weights: pairs 96..127 (cols 192..255), 8 groups of 4 pairs.
    for (int jg=0;jg<8;++jg){
      float4 a0 = *(const float4*)(pr0 + 192 + 8*jg);
      float4 a1 = *(const float4*)(pr0 + 192 + 8*jg + 4);
      wlds[jg][row0][0] = __builtin_bit_cast(unsigned, pack2(a0.x,a0.y));
      wlds[jg][row0][1] = __builtin_bit_cast(unsigned, pack2(a0.z,a0.w));
      wlds[jg][row0][2] = __builtin_bit_cast(unsigned, pack2(a1.x,a1.y));
      wlds[jg][row0][3] = __builtin_bit_cast(unsigned, pack2(a1.z,a1.w));
      float4 b0 = *(const float4*)(pr1 + 192 + 8*jg);
      float4 b1 = *(const float4*)(pr1 + 192 + 8*jg + 4);
      wlds[jg][row1][0] = __builtin_bit_cast(unsigned, pack2(b0.x,b0.y));
      wlds[jg][row1][1] = __builtin_bit_cast(unsigned, pack2(b0.z,b0.w));
      wlds[jg][row1][2] = __builtin_bit_cast(unsigned, pack2(b1.x,b1.y));
      wlds[jg][row1][3] = __builtin_bit_cast(unsigned, pack2(b1.z,b1.w));
    }
  }
  // h state: lane l holds pairs 2l (hp0) and 2l+1 (hp1) = units 4l..4l+3,
  // replicated across all 8 waves. Cell state likewise (c0..c3).
  unsigned hp0 = 0u, hp1 = 0u;
  float c0=0.f, c1=0.f, c2=0.f, c3=0.f;
  __syncthreads();

  int tf = d ? (LSEQ-1) : 0;
  float xga = xgd[(size_t)tf*1024 + row0];
  float xgb = xgd[(size_t)tf*1024 + row1];

  for (int s=0;s<LSEQ;++s){
    int par = s & 1;
    // --- dot: VGPR part, pairs 0..95 (pair p: lane p>>1, reg p&1)
    float a0 = xga, b0 = 0.f, a1 = xgb, b1 = 0.f;
    #pragma unroll
    for (int j=0;j<16;++j){
      unsigned h0v = __builtin_amdgcn_readlane(hp0, j);
      unsigned h1v = __builtin_amdgcn_readlane(hp1, j);
      a0 = __builtin_amdgcn_fdot2(h2(h0v), wA0[2*j],   a0, false);
      b0 = __builtin_amdgcn_fdot2(h2(h1v), wA0[2*j+1], b0, false);
      a1 = __builtin_amdgcn_fdot2(h2(h0v), wB0[2*j],   a1, false);
      b1 = __builtin_amdgcn_fdot2(h2(h1v), wB0[2*j+1], b1, false);
    }
    #pragma unroll
    for (int j=0;j<16;++j){
      unsigned h0v = __builtin_amdgcn_readlane(hp0, 16+j);
      unsigned h1v = __builtin_amdgcn_readlane(hp1, 16+j);
      a0 = __builtin_amdgcn_fdot2(h2(h0v), wA1[2*j],   a0, false);
      b0 = __builtin_amdgcn_fdot2(h2(h1v), wA1[2*j+1], b0, false);
      a1 = __builtin_amdgcn_fdot2(h2(h0v), wB1[2*j],   a1, false);
      b1 = __builtin_amdgcn_fdot2(h2(h1v), wB1[2*j+1], b1, false);
    }
    // --- xg prefetch for s+1 (fire-and-forget; wait lands next iteration)
    int tn = (s+1 < LSEQ) ? (d ? (LSEQ-2-s) : (s+1)) : tf;
    float nxa = xgd[(size_t)tn*1024 + row0];
    float nxb = xgd[(size_t)tn*1024 + row1];
    #pragma unroll
    for (int j=0;j<16;++j){
      unsigned h0v = __builtin_amdgcn_readlane(hp0, 32+j);
      unsigned h1v = __builtin_amdgcn_readlane(hp1, 32+j);
      a0 = __builtin_amdgcn_fdot2(h2(h0v), wA2[2*j],   a0, false);
      b0 = __builtin_amdgcn_fdot2(h2(h1v), wA2[2*j+1], b0, false);
      a1 = __builtin_amdgcn_fdot2(h2(h0v), wB2[2*j],   a1, false);
      b1 = __builtin_amdgcn_fdot2(h2(h1v), wB2[2*j+1], b1, false);
    }
    // --- dot: LDS part, pairs 96..127 (8 groups x 4 pairs, 2x b128/group)
    #pragma unroll
    for (int jg=0;jg<8;++jg){
      u32x4 ga = *(const u32x4*)&wlds[jg][row0][0];
      u32x4 gb = *(const u32x4*)&wlds[jg][row1][0];
      unsigned h0v = __builtin_amdgcn_readlane(hp0, 48+2*jg);
      unsigned h1v = __builtin_amdgcn_readlane(hp1, 48+2*jg);
      unsigned h2v = __builtin_amdgcn_readlane(hp0, 49+2*jg);
      unsigned h3v = __builtin_amdgcn_readlane(hp1, 49+2*jg);
      a0 = __builtin_amdgcn_fdot2(h2(h0v), h2(ga[0]), a0, false);
      b0 = __builtin_amdgcn_fdot2(h2(h1v), h2(ga[1]), b0, false);
      a0 = __builtin_amdgcn_fdot2(h2(h2v), h2(ga[2]), a0, false);
      b0 = __builtin_amdgcn_fdot2(h2(h3v), h2(ga[3]), b0, false);
      a1 = __builtin_amdgcn_fdot2(h2(h0v), h2(gb[0]), a1, false);
      b1 = __builtin_amdgcn_fdot2(h2(h1v), h2(gb[1]), b1, false);
      a1 = __builtin_amdgcn_fdot2(h2(h2v), h2(gb[2]), a1, false);
      b1 = __builtin_amdgcn_fdot2(h2(h3v), h2(gb[3]), b1, false);
    }
    float pre0 = a0 + b0, pre1 = a1 + b1;
    float act0 = sigm(pre0);                                // i or f
    float act1 = (t < 256) ? tanh_fast(pre1) : sigm(pre1);  // g or o
    gate_sh[par][row0] = act0;
    gate_sh[par][row1] = act1;
    wg_barrier();                    // gates(s) visible to all waves
    // --- update: units 4l..4l+3, replicated on ALL lanes of ALL waves
    {
      const float* gp = gate_sh[par];
      float4 gi = *(const float4*)&gp[       4*l];
      float4 gf = *(const float4*)&gp[256 +  4*l];
      float4 gg = *(const float4*)&gp[512 +  4*l];
      float4 go = *(const float4*)&gp[768 +  4*l];
      c0 = gf.x*c0 + gi.x*gg.x;
      c1 = gf.y*c1 + gi.y*gg.y;
      c2 = gf.z*c2 + gi.z*gg.z;
      c3 = gf.w*c3 + gi.w*gg.w;
      float h0 = go.x * tanh_fast(c0);
      float h1 = go.y * tanh_fast(c1);
      float h2_ = go.z * tanh_fast(c2);
      float h3 = go.w * tanh_fast(c3);
      hp0 = __builtin_bit_cast(unsigned, pack2(h0,h1));
      hp1 = __builtin_bit_cast(unsigned, pack2(h2_,h3));
    }
    // --- wave0: h-history store (fire-and-forget; nothing drains it)
    if (t < 64){
      int tp = d ? (LSEQ-1-s) : s;
      uint2 hv; hv.x = hp0; hv.y = hp1;
      *(uint2*)&hd[(size_t)tp*256 + 4*l] = hv;
    }
    xga = nxa; xgb = nxb;
    // no second barrier: next write targets gate_sh[par^1]; same-parity
    // reuse at s+2 is ordered by barrier(s+1) (see header comment).
  }
}

// K3: feats[t][tag] = b_out[tag] + [hf|hb] . w_out[tag]   (h history is f16)
__global__ void feats_kernel(
    const unsigned short* hstH, const float* w_out, const float* b_out,
    float* feats)
{
  __shared__ float w_sh[12*520];
  __shared__ float h_sh[16*520];
  const _Float16* hf = (const _Float16*)hstH;
  int tid=threadIdx.x;
  int t0=blockIdx.x*16;
  for (int i=tid;i<12*512;i+=256){ int tag=i>>9,k=i&511; w_sh[tag*520+k]=w_out[i]; }
  for (int i=tid;i<16*512;i+=256){
    int tt=i>>9,k=i&511;
    float v = (k<256)? (float)hf[(size_t)(t0+tt)*256+k]
                     : (float)hf[(size_t)(LSEQ+t0+tt)*256 + (k-256)];
    h_sh[tt*520+k]=v;
  }
  __syncthreads();
  if (tid<192){
    int tt=tid/12, tag=tid%12;
    const float* wr=&w_sh[tag*520];
    const float* hr=&h_sh[tt*520];
    float acc=b_out[tag];
    for (int k=0;k<512;k+=4){
      float4 a=*(const float4*)(wr+k);
      float4 b=*(const float4*)(hr+k);
      acc += a.x*b.x+a.y*b.y+a.z*b.z+a.w*b.w;
    }
    feats[(size_t)(t0+tt)*12+tag]=acc;
  }
}

// K4: Viterbi DP: feats in LDS, v register-resident via readlane; parallel
// block-composed backtrack.
__global__ void BiLSTM_CRF_14405320311361_kernel(
    const float* feats, const float* trans, float* outp)
{
  __shared__ float fsh[LSEQ*12];           // 96 KB
  __shared__ unsigned char bps[LSEQ*12];   // 24 KB
  __shared__ float term_sh[16];
  __shared__ int ibuf[66];
  __shared__ unsigned char fmap[64*12];
  int tid = threadIdx.x;
  for (int i=tid; i<LSEQ*12/4; i+=256)
    *(float4*)&fsh[4*i] = *(const float4*)&feats[4*i];
  __syncthreads();

  int lane = tid & 63;
  int fl = (lane<12) ? lane : 0;
  float vn = 0.f;
  if (tid < 64){
    float tr[12];
    #pragma unroll
    for (int p=0;p<12;++p) tr[p] = trans[fl*12+p];
    vn = (lane==10) ? 0.f : -10000.f;     // START=10
    float fa = fsh[fl];
    float fb = fsh[12+fl];
    for (int t=0;t<LSEQ;++t){
      unsigned vu = __float_as_uint(vn);
      float best; int bp; float sc;
      best = tr[0] + __uint_as_float(__builtin_amdgcn_readlane(vu,0)); bp = 0;
      sc = tr[1]  + __uint_as_float(__builtin_amdgcn_readlane(vu,1));  if(sc>best){best=sc;bp=1;}
      sc = tr[2]  + __uint_as_float(__builtin_amdgcn_readlane(vu,2));  if(sc>best){best=sc;bp=2;}
      sc = tr[3]  + __uint_as_float(__builtin_amdgcn_readlane(vu,3));  if(sc>best){best=sc;bp=3;}
      sc = tr[4]  + __uint_as_float(__builtin_amdgcn_readlane(vu,4));  if(sc>best){best=sc;bp=4;}
      sc = tr[5]  + __uint_as_float(__builtin_amdgcn_readlane(vu,5));  if(sc>best){best=sc;bp=5;}
      sc = tr[6]  + __uint_as_float(__builtin_amdgcn_readlane(vu,6));  if(sc>best){best=sc;bp=6;}
      sc = tr[7]  + __uint_as_float(__builtin_amdgcn_readlane(vu,7));  if(sc>best){best=sc;bp=7;}
      sc = tr[8]  + __uint_as_float(__builtin_amdgcn_readlane(vu,8));  if(sc>best){best=sc;bp=8;}
      sc = tr[9]  + __uint_as_float(__builtin_amdgcn_readlane(vu,9));  if(sc>best){best=sc;bp=9;}
      sc = tr[10] + __uint_as_float(__builtin_amdgcn_readlane(vu,10)); if(sc>best){best=sc;bp=10;}
      sc = tr[11] + __uint_as_float(__builtin_amdgcn_readlane(vu,11)); if(sc>best){best=sc;bp=11;}
      vn = best + fa;
      fa = fb;
      if (t+2 < LSEQ) fb = fsh[(t+2)*12+fl];
      if (lane<12) bps[t*12+lane] = (unsigned char)bp;
    }
  }
  if (tid < 12) term_sh[tid] = vn + trans[11*12+tid];   // STOP=11
  __syncthreads();
  if (tid == 0){
    float bs=term_sh[0]; int bt=0;
    for (int p=1;p<12;++p){ if (term_sh[p]>bs){bs=term_sh[p];bt=p;} }
    outp[0] = bs;
    ibuf[64] = bt;
  }
  __syncthreads();
  if (tid < 64){
    int b = tid;
    int f[12];
    int thi = b*32+31;
    #pragma unroll
    for (int x=0;x<12;++x) f[x] = bps[thi*12+x];
    for (int t=thi-1; t>=b*32; --t){
      int base = t*12;
      #pragma unroll
      for (int x=0;x<12;++x) f[x] = bps[base + f[x]];
    }
    #pragma unroll
    for (int x=0;x<12;++x) fmap[b*12+x] = (unsigned char)f[x];
  }
  __syncthreads();
  if (tid == 0){
    int tag = ibuf[64];
    for (int b=63;b>=0;--b){ ibuf[b]=tag; tag = fmap[b*12+tag]; }
  }
  __syncthreads();
  if (tid < 64){
    int b = tid;
    int tag = ibuf[b];
    for (int t=b*32+31; t>=b*32; --t){
      outp[1+t] = (float)tag;
      tag = bps[t*12+tag];
    }
  }
}

extern "C" void kernel_launch(void* const* d_in, const int* in_sizes, int n_in,
                              void* d_out, int out_size, void* d_ws, size_t ws_size,
                              hipStream_t stream) {
  const int*   sent   = (const int*)d_in[0];
  const float* embed  = (const float*)d_in[1];
  const float* w_ih_f = (const float*)d_in[2];
  const float* w_hh_f = (const float*)d_in[3];
  const float* b_ih_f = (const float*)d_in[4];
  const float* b_hh_f = (const float*)d_in[5];
  const float* w_ih_b = (const float*)d_in[6];
  const float* w_hh_b = (const float*)d_in[7];
  const float* b_ih_b = (const float*)d_in[8];
  const float* b_hh_b = (const float*)d_in[9];
  const float* w_out  = (const float*)d_in[10];
  const float* b_out  = (const float*)d_in[11];
  const float* trans  = (const float*)d_in[12];

  float* xg = (float*)d_ws;                                           // [2][L][1024] f32 = 16 MB
  unsigned short* hstH = (unsigned short*)(xg + (size_t)2*LSEQ*1024); // [2][L][256] f16 = 2 MB
  float* feats = (float*)(hstH + (size_t)2*LSEQ*256);                 // [L][12] f32 = 96 KB
  float* outp  = (float*)d_out;

  xg_kernel<<<dim3(LSEQ/8), dim3(256), 0, stream>>>(
      sent, embed, w_ih_f, b_ih_f, b_hh_f, w_ih_b, b_ih_b, b_hh_b, xg);
  lstm_rec<<<dim3(2), dim3(512), 0, stream>>>(w_hh_f, w_hh_b, xg, hstH);
  feats_kernel<<<dim3(LSEQ/16), dim3(256), 0, stream>>>(hstH, w_out, b_out, feats);
  BiLSTM_CRF_14405320311361_kernel<<<dim3(1), dim3(256), 0, stream>>>(feats, trans, outp);
}